// Round 7
// baseline (124.102 us; speedup 1.0000x reference)
//
#include <hip/hip_runtime.h>
#include <hip/hip_bf16.h>

// DiffusionGraphConv on MI355X (gfx950), bf16 MFMA pipeline, round 7.
//
// Pipeline (3 launches):
//   prep (fused): cvt_sup | sup_t(from f32) | w2t | pack
//   psq  (128x32 2-phase GEMM): Pstack = [A1; 2A1^2-I; A2; 2A2^2-I]
//   mega (fused, DUAL-BAND): per band-pair s in {0,1}:
//            K-sweep: yacc[p] = x0t_tile @ P_{2s+p}^T  (x0t staged ONCE,
//                     af fragments shared by both bands -> ds_read/MFMA -24%,
//                     barriers per sweep halved)
//            per band, per f-half h: yacc -> Bt2h LDS (16KB), then
//                     out^T[o][n] += w2t_slice @ Bt2h   (K=64)
//        then out^T += w2t_m0 @ X0nf-tile, + bias -> d_out
//
// LDS 64KB: A-stage 16KB | B-stage dual 32KB | Bt2h 16KB -> 2 blocks/CU.
// VGPR: yacc 128 + oacc 64 + frags ~= 230; __launch_bounds__(256,2) allows
// up to 256 without occupancy loss (8 waves/CU).
//
// ws layout (bf16 elems):
//   PSTK 4M | SUPT 2M | X0T 8M | X0NF 8M | (XNF unused) | W2T 80K

typedef short bf16x8  __attribute__((ext_vector_type(8)));
typedef short short4v __attribute__((ext_vector_type(4)));
typedef float f32x4   __attribute__((ext_vector_type(4)));

constexpr size_t MB1    = 1024ull * 1024ull;
constexpr size_t SZ_MAT = 8192ull * 1024ull;
constexpr size_t OFF_PSTK = 0;
constexpr size_t OFF_SUPT = 4 * MB1;
constexpr size_t OFF_X0T  = 6 * MB1;
constexpr size_t OFF_X0NF = OFF_X0T  + SZ_MAT;
constexpr size_t OFF_XNF  = OFF_X0NF + SZ_MAT;
constexpr size_t OFF_W2T  = OFF_XNF  + 4 * SZ_MAT;

__device__ __forceinline__ unsigned short f2bf(float x) {
  union { float f; unsigned int u; } v; v.f = x;
  unsigned int r = v.u + 0x7fffu + ((v.u >> 16) & 1u);   // RNE
  return (unsigned short)(r >> 16);
}

#define GLD16(gp, lp)                                                         \
  __builtin_amdgcn_global_load_lds(                                           \
      (const __attribute__((address_space(1))) unsigned int*)(gp),            \
      (__attribute__((address_space(3))) unsigned int*)(lp), 16, 0, 0)

// ---------------- fused prep kernel (unchanged) ----------------

__global__ __launch_bounds__(256)
void prep_kernel(const float* __restrict__ sup,
                 const float* __restrict__ weight,
                 const float* __restrict__ inputs,
                 const float* __restrict__ state,
                 unsigned short* __restrict__ ws) {
  __shared__ unsigned short tile[64][65];
  int bid = blockIdx.x;
  int tl  = threadIdx.x;

  if (bid < 2048) {                       // ---- cvt_sup
    size_t t = (size_t)bid * 256 + tl;
    const float4* src = (const float4*)sup;
    float4 v = src[t];
    size_t e = t * 4;
    size_t s = e >> 20;
    size_t r = e & (MB1 - 1);
    short4v o; o[0] = (short)f2bf(v.x); o[1] = (short)f2bf(v.y);
    o[2] = (short)f2bf(v.z); o[3] = (short)f2bf(v.w);
    *(short4v*)&ws[OFF_PSTK + 2 * s * MB1 + r] = o;
  } else if (bid < 2560) {                // ---- sup_t (from f32 source)
    int i = bid - 2048;
    int nt = i & 15, mt = (i >> 4) & 15, s = i >> 8;
    const float* A = sup + (size_t)s * MB1;
    unsigned short* AT = ws + OFF_SUPT + (size_t)s * MB1;
    int cl = tl & 63, rg = tl >> 6;
#pragma unroll 4
    for (int rr = 0; rr < 16; ++rr) {
      int rl = rr * 4 + rg;
      tile[rl][cl] = f2bf(A[(size_t)(nt * 64 + rl) * 1024 + mt * 64 + cl]);
    }
    __syncthreads();
#pragma unroll 4
    for (int rr = 0; rr < 16; ++rr) {
      int ml = rr * 4 + rg;
      AT[(size_t)(mt * 64 + ml) * 1024 + nt * 64 + cl] = tile[cl][ml];
    }
  } else if (bid < 2880) {                // ---- w2t
    int t = (bid - 2560) * 256 + tl;
    int o = t / 640, k = t % 640;
    int m = k >> 7, f = k & 127;
    ws[OFF_W2T + t] = f2bf(weight[(f * 5 + m) * 128 + o]);
  } else {                                // ---- pack
    int i = bid - 2880;
    int b = i & 63, nt = (i >> 6) & 15, ft = i >> 10;
    const float* src = ft ? state : inputs;
    unsigned short* x0t  = ws + OFF_X0T;
    unsigned short* x0nf = ws + OFF_X0NF;
    int fl = tl & 63, nr = tl >> 6;
#pragma unroll 4
    for (int rr = 0; rr < 16; ++rr) {
      int n_loc = rr * 4 + nr;
      float v = src[(size_t)b * 65536 + (size_t)(nt * 64 + n_loc) * 64 + fl];
      unsigned short bv = f2bf(v);
      tile[n_loc][fl] = bv;
      x0nf[(size_t)(nt * 64 + n_loc) * 8192 + b * 128 + ft * 64 + fl] = bv;
    }
    __syncthreads();
#pragma unroll 4
    for (int rr = 0; rr < 16; ++rr) {
      int f_loc = rr * 4 + nr;
      x0t[(size_t)(b * 128 + ft * 64 + f_loc) * 1024 + nt * 64 + fl] =
          tile[fl][f_loc];
    }
  }
}

// ---------------- mega kernel: dual-band diffusion + output fused ---------
// 256 thr (4 waves 2x2), block tile 128(bf) x 128(n).
// LDS (elems): A [0,8192) | B dual [8192,24576) | Bt2h [24576,32768)

__global__ __launch_bounds__(256, 2)
void mega_kernel(unsigned short* __restrict__ ws,
                 const float* __restrict__ bias,
                 float* __restrict__ dout) {
  extern __shared__ unsigned short lds[];   // 65536 B

  const unsigned short* X0T = ws + OFF_X0T;    // [(b,f)=8192][1024]
  const unsigned short* X0N = ws + OFF_X0NF;   // [n=1024][(b,f)=8192]
  const unsigned short* W2  = ws + OFF_W2T;    // [o=128][640]

  const int tid = threadIdx.x;
  const int l   = tid & 63;
  const int w   = tid >> 6;
  const int wr  = w >> 1, wc = w & 1;
  const int lm  = l & 15, q = l >> 4;

  // grid 512 = 64 bf-tiles x 8 n-tiles; XCD owns an 8x8 rect.
  int bid = blockIdx.x;
  int xcd = bid & 7, idx = bid >> 3;
  const int bm = xcd * 8 + (idx & 7);    // bf-tile = batch b (0..63)
  const int bn = idx >> 3;               // n-tile (0..7)

  const int subrow = l >> 3;
  const int koff   = (((l & 7) << 3) ^ (subrow << 3));

  auto stage_x0t = [&](int kt) {         // A <- x0t rows bf-tile
#pragma unroll
    for (int c = 0; c < 4; ++c) {
      int chunk = w * 4 + c, rowl = chunk * 8 + subrow;
      const unsigned short* gp =
          X0T + (size_t)(bm * 128 + rowl) * 1024 + kt * 64 + koff;
      GLD16(gp, &lds[chunk * 512]);
    }
  };
  auto stage_P = [&](int band, int kt, int slot) {  // B[slot] <- P band rows
#pragma unroll
    for (int c = 0; c < 4; ++c) {
      int chunk = w * 4 + c, rowl = chunk * 8 + subrow;
      const unsigned short* gp = ws + OFF_PSTK + (size_t)band * MB1 +
                                 (size_t)(bn * 128 + rowl) * 1024 + kt * 64 + koff;
      GLD16(gp, &lds[8192 + slot * 8192 + chunk * 512]);
    }
  };
  auto stage_w2 = [&](int m, int h) {    // A <- w2t rows o, k-slice (m, half h)
#pragma unroll
    for (int c = 0; c < 4; ++c) {
      int chunk = w * 4 + c, rowl = chunk * 8 + subrow;
      const unsigned short* gp =
          W2 + (size_t)rowl * 640 + m * 128 + h * 64 + koff;
      GLD16(gp, &lds[chunk * 512]);
    }
  };
  auto stage_x0n = [&](int kt2) {        // B[0] <- x0nf rows n-tile, b=bm
#pragma unroll
    for (int c = 0; c < 4; ++c) {
      int chunk = w * 4 + c, rowl = chunk * 8 + subrow;
      const unsigned short* gp =
          X0N + (size_t)(bn * 128 + rowl) * 8192 + bm * 128 + kt2 * 64 + koff;
      GLD16(gp, &lds[8192 + chunk * 512]);
    }
  };

  f32x4 oacc[4][4] = {};

  for (int s = 0; s < 2; ++s) {
    // ---- dual-band K-sweep: yacc[p] = x0t_tile @ P_{2s+p}^T ----
    f32x4 yacc[2][4][4] = {};
    for (int kt = 0; kt < 16; ++kt) {
      stage_x0t(kt);
      stage_P(2 * s + 0, kt, 0);
      stage_P(2 * s + 1, kt, 1);
      __syncthreads();
#pragma unroll
      for (int kk = 0; kk < 2; ++kk) {
        bf16x8 af[4];
#pragma unroll
        for (int i = 0; i < 4; ++i) {
          int row = wr * 64 + i * 16 + lm;
          int off = row * 64 + ((kk * 32 + (q << 3)) ^ ((row & 7) << 3));
          af[i] = *(const bf16x8*)&lds[off];
        }
#pragma unroll
        for (int p = 0; p < 2; ++p) {
#pragma unroll
          for (int j = 0; j < 4; ++j) {
            int row = wc * 64 + j * 16 + lm;
            int off = 8192 + p * 8192 + row * 64 +
                      ((kk * 32 + (q << 3)) ^ ((row & 7) << 3));
            bf16x8 bfv = *(const bf16x8*)&lds[off];
#pragma unroll
            for (int i = 0; i < 4; ++i)
              yacc[p][i][j] = __builtin_amdgcn_mfma_f32_16x16x32_bf16(
                  af[i], bfv, yacc[p][i][j], 0, 0, 0);
          }
        }
      }
      __syncthreads();
    }

    // ---- out-contract both bands, f-half streamed through 16KB Bt2h ----
#pragma unroll
    for (int p = 0; p < 2; ++p) {
      int band = 2 * s + p;
#pragma unroll
      for (int h = 0; h < 2; ++h) {
        stage_w2(band + 1, h);           // A-stage free (guarded by prev sync)
        if (wr == h) {
          // this wave's yacc covers f = h*64 + (i*16 + q*4 + r)
#pragma unroll
          for (int i = 0; i < 4; ++i) {
            int fh0 = i * 16 + q * 4;
#pragma unroll
            for (int j = 0; j < 4; ++j) {
              int n = wc * 64 + j * 16 + lm;
              short4v pk;
#pragma unroll
              for (int r = 0; r < 4; ++r) pk[r] = (short)f2bf(yacc[p][i][j][r]);
              *(short4v*)&lds[24576 + n * 64 + ((((fh0 >> 3) ^ (n & 7))) << 3) +
                              (fh0 & 7)] = pk;
            }
          }
        }
        __syncthreads();
#pragma unroll
        for (int kk = 0; kk < 2; ++kk) {
          bf16x8 af[4], bfv[4];
#pragma unroll
          for (int i = 0; i < 4; ++i) {
            int row = wr * 64 + i * 16 + lm;             // o
            int off = row * 64 + ((kk * 32 + (q << 3)) ^ ((row & 7) << 3));
            af[i] = *(const bf16x8*)&lds[off];
          }
#pragma unroll
          for (int j = 0; j < 4; ++j) {
            int n = wc * 64 + j * 16 + lm;
            int g = kk * 4 + q;                          // fh granule
            bfv[j] = *(const bf16x8*)&lds[24576 + n * 64 + ((g ^ (n & 7)) << 3)];
          }
#pragma unroll
          for (int i = 0; i < 4; ++i)
#pragma unroll
            for (int j = 0; j < 4; ++j)
              oacc[i][j] = __builtin_amdgcn_mfma_f32_16x16x32_bf16(
                  af[i], bfv[j], oacc[i][j], 0, 0, 0);
        }
        __syncthreads();
      }
    }
  }

  // ---- m=0 term: out^T += w2t[m=0] @ X0nf-tile  (K=128, 2 kt) ----
#pragma unroll
  for (int kt2 = 0; kt2 < 2; ++kt2) {
    stage_w2(0, kt2);
    stage_x0n(kt2);
    __syncthreads();
#pragma unroll
    for (int kk = 0; kk < 2; ++kk) {
      bf16x8 af[4], bfv[4];
#pragma unroll
      for (int i = 0; i < 4; ++i) {
        int row = wr * 64 + i * 16 + lm;               // o
        int off = row * 64 + ((kk * 32 + (q << 3)) ^ ((row & 7) << 3));
        af[i] = *(const bf16x8*)&lds[off];
      }
#pragma unroll
      for (int j = 0; j < 4; ++j) {
        int row = wc * 64 + j * 16 + lm;               // n
        int off = 8192 + row * 64 + ((kk * 32 + (q << 3)) ^ ((row & 7) << 3));
        bfv[j] = *(const bf16x8*)&lds[off];
      }
#pragma unroll
      for (int i = 0; i < 4; ++i)
#pragma unroll
        for (int j = 0; j < 4; ++j)
          oacc[i][j] = __builtin_amdgcn_mfma_f32_16x16x32_bf16(
              af[i], bfv[j], oacc[i][j], 0, 0, 0);
    }
    __syncthreads();
  }

  // ---- epilogue: out[b][n*128+o] = out^T[o][n] + bias[o] ----
#pragma unroll
  for (int i = 0; i < 4; ++i) {
    int o0 = wr * 64 + i * 16 + q * 4;                 // 4 consecutive o
    float4 bv = *(const float4*)&bias[o0];
#pragma unroll
    for (int j = 0; j < 4; ++j) {
      int n = bn * 128 + wc * 64 + j * 16 + lm;
      float4 v;
      v.x = oacc[i][j][0] + bv.x;
      v.y = oacc[i][j][1] + bv.y;
      v.z = oacc[i][j][2] + bv.z;
      v.w = oacc[i][j][3] + bv.w;
      *(float4*)&dout[(size_t)bm * 131072 + (size_t)n * 128 + o0] = v;
    }
  }
}

// ---------------- psq: 128x32 2-phase GEMM (unchanged) ----------

__global__ __launch_bounds__(256)
void psq_kernel(unsigned short* __restrict__ ws) {
  __shared__ short At[128 * 64];
  __shared__ short Bt[32 * 64];

  const int tid = threadIdx.x;
  const int l   = tid & 63;
  const int w   = tid >> 6;
  const int wr  = w >> 1, wc = w & 1;

  const int bm = blockIdx.x, bn = blockIdx.y, s = blockIdx.z;
  const unsigned short* A = ws + OFF_PSTK + (size_t)(2 * s) * MB1;
  const unsigned short* B = ws + OFF_SUPT + (size_t)s * MB1;

  const int subrow = l >> 3;
  const int koff   = (((l & 7) << 3) ^ (subrow << 3));

  f32x4 acc[4][1] = {};

  for (int kt = 0; kt < 16; ++kt) {
#pragma unroll
    for (int c = 0; c < 4; ++c) {
      int chunk = w * 4 + c, rowl = chunk * 8 + subrow;
      GLD16(A + (size_t)(bm * 128 + rowl) * 1024 + kt * 64 + koff,
            &At[chunk * 512]);
    }
    {
      int chunk = w, rowl = chunk * 8 + subrow;
      GLD16(B + (size_t)(bn * 32 + rowl) * 1024 + kt * 64 + koff,
            &Bt[chunk * 512]);
    }
    __syncthreads();

#pragma unroll
    for (int kk = 0; kk < 2; ++kk) {
      bf16x8 af[4], bfv;
#pragma unroll
      for (int i = 0; i < 4; ++i) {
        int row = wr * 64 + i * 16 + (l & 15);
        int off = row * 64 + ((kk * 32 + ((l >> 4) << 3)) ^ ((row & 7) << 3));
        af[i] = *(const bf16x8*)&At[off];
      }
      {
        int row = wc * 16 + (l & 15);
        int off = row * 64 + ((kk * 32 + ((l >> 4) << 3)) ^ ((row & 7) << 3));
        bfv = *(const bf16x8*)&Bt[off];
      }
#pragma unroll
      for (int i = 0; i < 4; ++i)
        acc[i][0] = __builtin_amdgcn_mfma_f32_16x16x32_bf16(af[i], bfv,
                                                            acc[i][0], 0, 0, 0);
    }
    __syncthreads();
  }

  unsigned short* P = ws + OFF_PSTK + (size_t)(2 * s + 1) * MB1;
#pragma unroll
  for (int i = 0; i < 4; ++i) {
    int rg0 = bm * 128 + wr * 64 + i * 16 + ((l >> 4) << 2);
    int cg  = bn * 32 + wc * 16 + (l & 15);
#pragma unroll
    for (int r = 0; r < 4; ++r) {
      int rg = rg0 + r;
      float v = 2.0f * acc[i][0][r] - (rg == cg ? 1.0f : 0.0f);
      P[(size_t)rg * 1024 + cg] = f2bf(v);
    }
  }
}

// ---------------- launcher ----------------

extern "C" void kernel_launch(void* const* d_in, const int* in_sizes, int n_in,
                              void* d_out, int out_size, void* d_ws, size_t ws_size,
                              hipStream_t stream) {
  (void)in_sizes; (void)n_in; (void)out_size; (void)ws_size;
  const float* supports = (const float*)d_in[0];
  const float* inputs   = (const float*)d_in[1];
  const float* state    = (const float*)d_in[2];
  const float* weight   = (const float*)d_in[3];
  const float* bias     = (const float*)d_in[4];
  float* out = (float*)d_out;
  unsigned short* ws = (unsigned short*)d_ws;

  prep_kernel<<<4928, 256, 0, stream>>>(supports, weight, inputs, state, ws);
  psq_kernel<<<dim3(8, 32, 2), 256, 0, stream>>>(ws);
  mega_kernel<<<512, 256, 65536, stream>>>(ws, bias, out);
}

// Round 8
// 111.662 us; speedup vs baseline: 1.1114x; 1.1114x over previous
//
#include <hip/hip_runtime.h>
#include <hip/hip_bf16.h>

// DiffusionGraphConv on MI355X (gfx950), bf16 MFMA pipeline, round 8.
// = Round 6 structure (best: 113.7us) + prep reads supports ONCE.
//
// Pipeline (3 launches):
//   prep (fused): sup_cvt+t (one f32 read -> bf16 copy + transpose) | w2t | pack
//   psq  (128x32 2-phase GEMM): Pstack = [A1; 2A1^2-I; A2; 2A2^2-I]
//   mega (2-phase GEMM, fused): per band m'=1..4:
//            Yt[(b,f)][n] = x0t_tile @ Pband^T      (K=1024, 16 kt)
//            Yt -> LDS Bt2[n][f] (bf16, swizzled)   (no HBM round-trip)
//            out^T[o][n] += w2t_band @ Bt2          (K=128, 2 kt)
//        then out^T += w2t_m0 @ X0nf-tile, + bias -> d_out
//
// ws layout (bf16 elems):
//   PSTK 4M | SUPT 2M | X0T 8M | X0NF 8M | (XNF unused) | W2T 80K

typedef short bf16x8  __attribute__((ext_vector_type(8)));
typedef short short4v __attribute__((ext_vector_type(4)));
typedef float f32x4   __attribute__((ext_vector_type(4)));

constexpr size_t MB1    = 1024ull * 1024ull;
constexpr size_t SZ_MAT = 8192ull * 1024ull;
constexpr size_t OFF_PSTK = 0;
constexpr size_t OFF_SUPT = 4 * MB1;
constexpr size_t OFF_X0T  = 6 * MB1;
constexpr size_t OFF_X0NF = OFF_X0T  + SZ_MAT;
constexpr size_t OFF_XNF  = OFF_X0NF + SZ_MAT;
constexpr size_t OFF_W2T  = OFF_XNF  + 4 * SZ_MAT;

__device__ __forceinline__ unsigned short f2bf(float x) {
  union { float f; unsigned int u; } v; v.f = x;
  unsigned int r = v.u + 0x7fffu + ((v.u >> 16) & 1u);   // RNE
  return (unsigned short)(r >> 16);
}

#define GLD16(gp, lp)                                                         \
  __builtin_amdgcn_global_load_lds(                                           \
      (const __attribute__((address_space(1))) unsigned int*)(gp),            \
      (__attribute__((address_space(3))) unsigned int*)(lp), 16, 0, 0)

// ---------------- fused prep kernel ----------------
// grid 2880 x 256thr:
//   [0,512)     sup_cvt+t : one f32 tile read -> bf16 PSTK rows 0,2 AND SUPT^T
//   [512,832)   w2t       : weight repack [o][m*128+f]
//   [832,2880)  pack      : x0nf + x0t from inputs/state

__global__ __launch_bounds__(256)
void prep_kernel(const float* __restrict__ sup,
                 const float* __restrict__ weight,
                 const float* __restrict__ inputs,
                 const float* __restrict__ state,
                 unsigned short* __restrict__ ws) {
  __shared__ unsigned short tile[64][65];
  int bid = blockIdx.x;
  int tl  = threadIdx.x;

  if (bid < 512) {                        // ---- sup cvt + transpose
    int nt = bid & 15, mt = (bid >> 4) & 15, s = bid >> 8;
    const float* A = sup + (size_t)s * MB1;
    unsigned short* AC = ws + OFF_PSTK + (size_t)(2 * s) * MB1;  // straight
    unsigned short* AT = ws + OFF_SUPT + (size_t)s * MB1;        // transposed
    int cl = tl & 63, rg = tl >> 6;
#pragma unroll 4
    for (int rr = 0; rr < 16; ++rr) {
      int rl = rr * 4 + rg;
      unsigned short bv =
          f2bf(A[(size_t)(nt * 64 + rl) * 1024 + mt * 64 + cl]);
      tile[rl][cl] = bv;
      AC[(size_t)(nt * 64 + rl) * 1024 + mt * 64 + cl] = bv;
    }
    __syncthreads();
#pragma unroll 4
    for (int rr = 0; rr < 16; ++rr) {
      int ml = rr * 4 + rg;
      AT[(size_t)(mt * 64 + ml) * 1024 + nt * 64 + cl] = tile[cl][ml];
    }
  } else if (bid < 832) {                 // ---- w2t
    int t = (bid - 512) * 256 + tl;       // < 81920
    int o = t / 640, k = t % 640;
    int m = k >> 7, f = k & 127;
    ws[OFF_W2T + t] = f2bf(weight[(f * 5 + m) * 128 + o]);
  } else {                                // ---- pack
    int i = bid - 832;                    // < 2048
    int b = i & 63, nt = (i >> 6) & 15, ft = i >> 10;
    const float* src = ft ? state : inputs;
    unsigned short* x0t  = ws + OFF_X0T;
    unsigned short* x0nf = ws + OFF_X0NF;
    int fl = tl & 63, nr = tl >> 6;
#pragma unroll 4
    for (int rr = 0; rr < 16; ++rr) {
      int n_loc = rr * 4 + nr;
      float v = src[(size_t)b * 65536 + (size_t)(nt * 64 + n_loc) * 64 + fl];
      unsigned short bv = f2bf(v);
      tile[n_loc][fl] = bv;
      x0nf[(size_t)(nt * 64 + n_loc) * 8192 + b * 128 + ft * 64 + fl] = bv;
    }
    __syncthreads();
#pragma unroll 4
    for (int rr = 0; rr < 16; ++rr) {
      int f_loc = rr * 4 + nr;
      x0t[(size_t)(b * 128 + ft * 64 + f_loc) * 1024 + nt * 64 + fl] =
          tile[fl][f_loc];
    }
  }
}

// ---------------- mega kernel (exact round-6 version) ---------------------
// 256 thr (4 waves 2x2), block tile 128(bf) x 128(n).
// LDS (elems): A-stage [0,8192) | B-stage [8192,16384) | Bt2 [16384,32768)

__global__ __launch_bounds__(256, 2)
void mega_kernel(unsigned short* __restrict__ ws,
                 const float* __restrict__ bias,
                 float* __restrict__ dout) {
  extern __shared__ unsigned short lds[];   // 65536 B

  const unsigned short* X0T = ws + OFF_X0T;    // [(b,f)=8192][1024]
  const unsigned short* X0N = ws + OFF_X0NF;   // [n=1024][(b,f)=8192]
  const unsigned short* W2  = ws + OFF_W2T;    // [o=128][640]

  const int tid = threadIdx.x;
  const int l   = tid & 63;
  const int w   = tid >> 6;
  const int wr  = w >> 1, wc = w & 1;
  const int lm  = l & 15, q = l >> 4;

  // grid 512 = 64 bf-tiles x 8 n-tiles; XCD owns an 8x8 rect.
  int bid = blockIdx.x;
  int xcd = bid & 7, idx = bid >> 3;
  const int bm = xcd * 8 + (idx & 7);    // bf-tile = batch b (0..63)
  const int bn = idx >> 3;               // n-tile (0..7)

  const int subrow = l >> 3;
  const int koff   = (((l & 7) << 3) ^ (subrow << 3));

  auto stage_x0t = [&](int kt) {
#pragma unroll
    for (int c = 0; c < 4; ++c) {
      int chunk = w * 4 + c, rowl = chunk * 8 + subrow;
      const unsigned short* gp =
          X0T + (size_t)(bm * 128 + rowl) * 1024 + kt * 64 + koff;
      GLD16(gp, &lds[chunk * 512]);
    }
  };
  auto stage_P = [&](int band, int kt) {
#pragma unroll
    for (int c = 0; c < 4; ++c) {
      int chunk = w * 4 + c, rowl = chunk * 8 + subrow;
      const unsigned short* gp = ws + OFF_PSTK + (size_t)band * MB1 +
                                 (size_t)(bn * 128 + rowl) * 1024 + kt * 64 + koff;
      GLD16(gp, &lds[8192 + chunk * 512]);
    }
  };
  auto stage_w2 = [&](int m, int kt2) {
#pragma unroll
    for (int c = 0; c < 4; ++c) {
      int chunk = w * 4 + c, rowl = chunk * 8 + subrow;
      const unsigned short* gp =
          W2 + (size_t)rowl * 640 + m * 128 + kt2 * 64 + koff;
      GLD16(gp, &lds[chunk * 512]);
    }
  };
  auto stage_x0n = [&](int kt2) {
#pragma unroll
    for (int c = 0; c < 4; ++c) {
      int chunk = w * 4 + c, rowl = chunk * 8 + subrow;
      const unsigned short* gp =
          X0N + (size_t)(bn * 128 + rowl) * 8192 + bm * 128 + kt2 * 64 + koff;
      GLD16(gp, &lds[8192 + chunk * 512]);
    }
  };

  f32x4 oacc[4][4] = {};

  for (int band = 0; band < 4; ++band) {
    // ---- Yt tile = x0t_tile @ Pband^T  (K=1024) ----
    f32x4 yacc[4][4] = {};
    for (int kt = 0; kt < 16; ++kt) {
      stage_x0t(kt);
      stage_P(band + 1 - 1 + 0, kt);   // band index in PSTK is `band` (0..3)
      __syncthreads();
#pragma unroll
      for (int kk = 0; kk < 2; ++kk) {
        bf16x8 af[4], bfv[4];
#pragma unroll
        for (int i = 0; i < 4; ++i) {
          int row = wr * 64 + i * 16 + lm;
          int off = row * 64 + ((kk * 32 + (q << 3)) ^ ((row & 7) << 3));
          af[i] = *(const bf16x8*)&lds[off];
        }
#pragma unroll
        for (int j = 0; j < 4; ++j) {
          int row = wc * 64 + j * 16 + lm;
          int off = 8192 + row * 64 + ((kk * 32 + (q << 3)) ^ ((row & 7) << 3));
          bfv[j] = *(const bf16x8*)&lds[off];
        }
#pragma unroll
        for (int i = 0; i < 4; ++i)
#pragma unroll
          for (int j = 0; j < 4; ++j)
            yacc[i][j] = __builtin_amdgcn_mfma_f32_16x16x32_bf16(
                af[i], bfv[j], yacc[i][j], 0, 0, 0);
      }
      __syncthreads();
    }

    // ---- Yt -> Bt2[n][f] bf16 (swizzled; 8B contiguous runs) ----
#pragma unroll
    for (int i = 0; i < 4; ++i) {
      int f0 = wr * 64 + i * 16 + q * 4;
#pragma unroll
      for (int j = 0; j < 4; ++j) {
        int n = wc * 64 + j * 16 + lm;
        short4v pk;
#pragma unroll
        for (int r = 0; r < 4; ++r) pk[r] = (short)f2bf(yacc[i][j][r]);
        *(short4v*)&lds[16384 + n * 128 + (((f0 >> 3) ^ (n & 7)) << 3) +
                        (f0 & 7)] = pk;
      }
    }
    __syncthreads();

    // ---- out^T += w2t[band m'] @ Bt2  (K=128, 2 kt) ----
#pragma unroll
    for (int kt2 = 0; kt2 < 2; ++kt2) {
      stage_w2(band + 1, kt2);
      __syncthreads();
#pragma unroll
      for (int kk = 0; kk < 2; ++kk) {
        bf16x8 af[4], bfv[4];
#pragma unroll
        for (int i = 0; i < 4; ++i) {
          int row = wr * 64 + i * 16 + lm;             // o
          int off = row * 64 + ((kk * 32 + (q << 3)) ^ ((row & 7) << 3));
          af[i] = *(const bf16x8*)&lds[off];
        }
#pragma unroll
        for (int j = 0; j < 4; ++j) {
          int n = wc * 64 + j * 16 + lm;
          int g = kt2 * 8 + kk * 4 + q;                // f granule
          bfv[j] = *(const bf16x8*)&lds[16384 + n * 128 + ((g ^ (n & 7)) << 3)];
        }
#pragma unroll
        for (int i = 0; i < 4; ++i)
#pragma unroll
          for (int j = 0; j < 4; ++j)
            oacc[i][j] = __builtin_amdgcn_mfma_f32_16x16x32_bf16(
                af[i], bfv[j], oacc[i][j], 0, 0, 0);
      }
      __syncthreads();
    }
  }

  // ---- m=0 term: out^T += w2t[m=0] @ X0nf-tile  (K=128, 2 kt) ----
#pragma unroll
  for (int kt2 = 0; kt2 < 2; ++kt2) {
    stage_w2(0, kt2);
    stage_x0n(kt2);
    __syncthreads();
#pragma unroll
    for (int kk = 0; kk < 2; ++kk) {
      bf16x8 af[4], bfv[4];
#pragma unroll
      for (int i = 0; i < 4; ++i) {
        int row = wr * 64 + i * 16 + lm;               // o
        int off = row * 64 + ((kk * 32 + (q << 3)) ^ ((row & 7) << 3));
        af[i] = *(const bf16x8*)&lds[off];
      }
#pragma unroll
      for (int j = 0; j < 4; ++j) {
        int row = wc * 64 + j * 16 + lm;               // n
        int off = 8192 + row * 64 + ((kk * 32 + (q << 3)) ^ ((row & 7) << 3));
        bfv[j] = *(const bf16x8*)&lds[off];
      }
#pragma unroll
      for (int i = 0; i < 4; ++i)
#pragma unroll
        for (int j = 0; j < 4; ++j)
          oacc[i][j] = __builtin_amdgcn_mfma_f32_16x16x32_bf16(
              af[i], bfv[j], oacc[i][j], 0, 0, 0);
    }
    __syncthreads();
  }

  // ---- epilogue: out[b][n*128+o] = out^T[o][n] + bias[o] ----
#pragma unroll
  for (int i = 0; i < 4; ++i) {
    int o0 = wr * 64 + i * 16 + q * 4;
    float4 bv = *(const float4*)&bias[o0];
#pragma unroll
    for (int j = 0; j < 4; ++j) {
      int n = bn * 128 + wc * 64 + j * 16 + lm;
      float4 v;
      v.x = oacc[i][j][0] + bv.x;
      v.y = oacc[i][j][1] + bv.y;
      v.z = oacc[i][j][2] + bv.z;
      v.w = oacc[i][j][3] + bv.w;
      *(float4*)&dout[(size_t)bm * 131072 + (size_t)n * 128 + o0] = v;
    }
  }
}

// ---------------- psq: 128x32 2-phase GEMM (unchanged) ----------

__global__ __launch_bounds__(256)
void psq_kernel(unsigned short* __restrict__ ws) {
  __shared__ short At[128 * 64];
  __shared__ short Bt[32 * 64];

  const int tid = threadIdx.x;
  const int l   = tid & 63;
  const int w   = tid >> 6;
  const int wr  = w >> 1, wc = w & 1;

  const int bm = blockIdx.x, bn = blockIdx.y, s = blockIdx.z;
  const unsigned short* A = ws + OFF_PSTK + (size_t)(2 * s) * MB1;
  const unsigned short* B = ws + OFF_SUPT + (size_t)s * MB1;

  const int subrow = l >> 3;
  const int koff   = (((l & 7) << 3) ^ (subrow << 3));

  f32x4 acc[4][1] = {};

  for (int kt = 0; kt < 16; ++kt) {
#pragma unroll
    for (int c = 0; c < 4; ++c) {
      int chunk = w * 4 + c, rowl = chunk * 8 + subrow;
      GLD16(A + (size_t)(bm * 128 + rowl) * 1024 + kt * 64 + koff,
            &At[chunk * 512]);
    }
    {
      int chunk = w, rowl = chunk * 8 + subrow;
      GLD16(B + (size_t)(bn * 32 + rowl) * 1024 + kt * 64 + koff,
            &Bt[chunk * 512]);
    }
    __syncthreads();

#pragma unroll
    for (int kk = 0; kk < 2; ++kk) {
      bf16x8 af[4], bfv;
#pragma unroll
      for (int i = 0; i < 4; ++i) {
        int row = wr * 64 + i * 16 + (l & 15);
        int off = row * 64 + ((kk * 32 + ((l >> 4) << 3)) ^ ((row & 7) << 3));
        af[i] = *(const bf16x8*)&At[off];
      }
      {
        int row = wc * 16 + (l & 15);
        int off = row * 64 + ((kk * 32 + ((l >> 4) << 3)) ^ ((row & 7) << 3));
        bfv = *(const bf16x8*)&Bt[off];
      }
#pragma unroll
      for (int i = 0; i < 4; ++i)
        acc[i][0] = __builtin_amdgcn_mfma_f32_16x16x32_bf16(af[i], bfv,
                                                            acc[i][0], 0, 0, 0);
    }
    __syncthreads();
  }

  unsigned short* P = ws + OFF_PSTK + (size_t)(2 * s + 1) * MB1;
#pragma unroll
  for (int i = 0; i < 4; ++i) {
    int rg0 = bm * 128 + wr * 64 + i * 16 + ((l >> 4) << 2);
    int cg  = bn * 32 + wc * 16 + (l & 15);
#pragma unroll
    for (int r = 0; r < 4; ++r) {
      int rg = rg0 + r;
      float v = 2.0f * acc[i][0][r] - (rg == cg ? 1.0f : 0.0f);
      P[(size_t)rg * 1024 + cg] = f2bf(v);
    }
  }
}

// ---------------- launcher ----------------

extern "C" void kernel_launch(void* const* d_in, const int* in_sizes, int n_in,
                              void* d_out, int out_size, void* d_ws, size_t ws_size,
                              hipStream_t stream) {
  (void)in_sizes; (void)n_in; (void)out_size; (void)ws_size;
  const float* supports = (const float*)d_in[0];
  const float* inputs   = (const float*)d_in[1];
  const float* state    = (const float*)d_in[2];
  const float* weight   = (const float*)d_in[3];
  const float* bias     = (const float*)d_in[4];
  float* out = (float*)d_out;
  unsigned short* ws = (unsigned short*)d_ws;

  prep_kernel<<<2880, 256, 0, stream>>>(supports, weight, inputs, state, ws);
  psq_kernel<<<dim3(8, 32, 2), 256, 0, stream>>>(ws);
  mega_kernel<<<512, 256, 65536, stream>>>(ws, bias, out);
}